// Round 6
// baseline (545.260 us; speedup 1.0000x reference)
//
#include <hip/hip_runtime.h>
#include <math.h>

#define NN   50000
#define EE   800000
#define INC  32
#define OUTC 256
#define NKB  132     // 1056/8 k-blocks: X kb0-3, H kb4-35, T1 36-67, T2 68-99, T3 100-131

using bf16x8 = __attribute__((ext_vector_type(8))) short;
using u16x8  = __attribute__((ext_vector_type(8))) unsigned short;
using f32x4  = __attribute__((ext_vector_type(4))) float;

struct __align__(8) Edge { int s; float w; };

__device__ __forceinline__ unsigned short f2b(float f) {
  union { float f; unsigned u; } v; v.f = f;
  return (unsigned short)((v.u + 0x7FFFu + ((v.u >> 16) & 1u)) >> 16);
}
__device__ __forceinline__ float b2f(unsigned short u) {
  union { unsigned u; float f; } v; v.u = ((unsigned)u) << 16; return v.f;
}

// ---------------- graph normalization + CSC build ----------------

__global__ void k_edge1(const int* __restrict__ ei, const float* __restrict__ ew,
                        float* __restrict__ deg, int* __restrict__ cnt) {
  for (int e = blockIdx.x * blockDim.x + threadIdx.x; e < EE;
       e += gridDim.x * blockDim.x) {
    atomicAdd(&deg[ei[e]], ew[e]);        // src degree
    atomicAdd(&cnt[ei[EE + e]], 1);       // dst histogram
  }
}

// hierarchical scan: 98 blocks x 512
__global__ __launch_bounds__(512) void k_scan1(const int* __restrict__ cnt,
                                               int* __restrict__ row_ptr,
                                               int* __restrict__ bsum) {
  __shared__ int sd[512];
  int t = threadIdx.x;
  int i = blockIdx.x * 512 + t;
  int x = (i < NN) ? cnt[i] : 0;
  sd[t] = x;
  __syncthreads();
  for (int off = 1; off < 512; off <<= 1) {
    int v = (t >= off) ? sd[t - off] : 0;
    __syncthreads();
    sd[t] += v;
    __syncthreads();
  }
  if (i < NN) row_ptr[i] = sd[t] - x;     // block-local exclusive
  if (t == 511) bsum[blockIdx.x] = sd[511];
}

__global__ __launch_bounds__(128) void k_scan2(int* __restrict__ bsum,
                                               int* __restrict__ row_ptr,
                                               int nblk) {
  __shared__ int sd[128];
  int t = threadIdx.x;
  int x = (t < nblk) ? bsum[t] : 0;
  sd[t] = x;
  __syncthreads();
  for (int off = 1; off < 128; off <<= 1) {
    int v = (t >= off) ? sd[t - off] : 0;
    __syncthreads();
    sd[t] += v;
    __syncthreads();
  }
  if (t < nblk) bsum[t] = sd[t] - x;      // exclusive
  if (t == 127) row_ptr[NN] = sd[127];
}

// adds block offsets; also finalizes dis = rsqrt(deg)
__global__ void k_scan3(int* __restrict__ row_ptr, const int* __restrict__ bsum,
                        int* __restrict__ nxt, float* __restrict__ deg) {
  int i = blockIdx.x * blockDim.x + threadIdx.x;
  if (i < NN) {
    int v = row_ptr[i] + bsum[i >> 9];
    row_ptr[i] = v;
    nxt[i] = v;
    float d = deg[i];
    deg[i] = d > 0.f ? rsqrtf(d) : 0.f;
  }
}

__global__ void k_fill(const int* __restrict__ ei, const float* __restrict__ ew,
                       const float* __restrict__ dis, int* __restrict__ nxt,
                       Edge* __restrict__ ev) {
  for (int e = blockIdx.x * blockDim.x + threadIdx.x; e < EE;
       e += gridDim.x * blockDim.x) {
    int s = ei[e], d = ei[EE + e];
    int pos = atomicAdd(&nxt[d], 1);
    Edge eg; eg.s = s; eg.w = -dis[s] * ew[e] * dis[d];  // -(2/lam)=-1, diag=0
    ev[pos] = eg;
  }
}

// -------- bf16 sparse prop: out = scale*(A~ x) - init (row-major only) --------
// 2 edges per wave-step: half = lane>>5 picks the edge, cl = lane&31 picks
// 8 cols (16B). Cross-half merge via shfl_xor(32); half 1 writes the result.

__global__ __launch_bounds__(256) void k_prop_bf(
    const int* __restrict__ row_ptr, const Edge* __restrict__ ev,
    const unsigned short* __restrict__ xb,
    const unsigned short* __restrict__ initb, float scale,
    unsigned short* __restrict__ outb) {
  int wid = blockIdx.x * 4 + (threadIdx.x >> 6);
  if (wid >= NN) return;
  int lane = threadIdx.x & 63;
  int half = lane >> 5;
  int cl = lane & 31;                       // col block: cols cl*8..cl*8+7
  int start = __builtin_amdgcn_readfirstlane(row_ptr[wid]);
  int end = __builtin_amdgcn_readfirstlane(row_ptr[wid + 1]);
  const size_t cofs = (size_t)(cl << 3);

  float a0[8], a1[8], a2[8], a3[8];
#pragma unroll
  for (int i = 0; i < 8; ++i) { a0[i] = 0.f; a1[i] = 0.f; a2[i] = 0.f; a3[i] = 0.f; }

  int j = start;
  for (; j + 7 < end; j += 8) {             // 8 edges per iter (4 per half)
    Edge e0 = ev[j + half];
    Edge e1 = ev[j + 2 + half];
    Edge e2 = ev[j + 4 + half];
    Edge e3 = ev[j + 6 + half];
    u16x8 u0 = *(const u16x8*)(xb + (size_t)e0.s * OUTC + cofs);
    u16x8 u1 = *(const u16x8*)(xb + (size_t)e1.s * OUTC + cofs);
    u16x8 u2 = *(const u16x8*)(xb + (size_t)e2.s * OUTC + cofs);
    u16x8 u3 = *(const u16x8*)(xb + (size_t)e3.s * OUTC + cofs);
#pragma unroll
    for (int i = 0; i < 8; ++i) {
      a0[i] = fmaf(e0.w, b2f(u0[i]), a0[i]);
      a1[i] = fmaf(e1.w, b2f(u1[i]), a1[i]);
      a2[i] = fmaf(e2.w, b2f(u2[i]), a2[i]);
      a3[i] = fmaf(e3.w, b2f(u3[i]), a3[i]);
    }
  }
  for (; j + 1 < end; j += 2) {             // pair tail
    Edge e0 = ev[j + half];
    u16x8 u0 = *(const u16x8*)(xb + (size_t)e0.s * OUTC + cofs);
#pragma unroll
    for (int i = 0; i < 8; ++i) a0[i] = fmaf(e0.w, b2f(u0[i]), a0[i]);
  }
  if (j < end) {                            // odd edge: half 0 only
    Edge e0 = ev[j];
    float wv = half ? 0.f : e0.w;
    u16x8 u0 = *(const u16x8*)(xb + (size_t)e0.s * OUTC + cofs);
#pragma unroll
    for (int i = 0; i < 8; ++i) a0[i] = fmaf(wv, b2f(u0[i]), a0[i]);
  }

  float o[8];
#pragma unroll
  for (int i = 0; i < 8; ++i) {
    float s = (a0[i] + a1[i]) + (a2[i] + a3[i]);
    s += __shfl_xor(s, 32);
    o[i] = s;
  }
  if (initb) {
    u16x8 iv = *(const u16x8*)(initb + (size_t)wid * OUTC + cofs);
#pragma unroll
    for (int i = 0; i < 8; ++i) o[i] = scale * o[i] - b2f(iv[i]);
  }
  if (half == 1) {
    u16x8 h;
#pragma unroll
    for (int i = 0; i < 8; ++i) h[i] = f2b(o[i]);
    *(u16x8*)(outb + (size_t)wid * OUTC + cofs) = h;
  }
}

// ---------------- bf16 packing of X+H (row-major, separate buffers) ----------------

__global__ void k_packXH(const float* __restrict__ X, const float* __restrict__ H,
                         unsigned short* __restrict__ xrm,
                         unsigned short* __restrict__ hrm) {
  int t = blockIdx.x * blockDim.x + threadIdx.x;   // NN*4 + NN*32
  if (t < NN * 4) {
    int row = t >> 2, kb = t & 3;
    float4 a = *(const float4*)(X + (size_t)row * INC + kb * 8);
    float4 b = *(const float4*)(X + (size_t)row * INC + kb * 8 + 4);
    u16x8 h;
    h[0] = f2b(a.x); h[1] = f2b(a.y); h[2] = f2b(a.z); h[3] = f2b(a.w);
    h[4] = f2b(b.x); h[5] = f2b(b.y); h[6] = f2b(b.z); h[7] = f2b(b.w);
    *(u16x8*)(xrm + (size_t)row * INC + kb * 8) = h;
  } else if (t < NN * 36) {
    int u = t - NN * 4;
    int row = u >> 5, kb = u & 31;
    float4 a = *(const float4*)(H + (size_t)row * OUTC + kb * 8);
    float4 b = *(const float4*)(H + (size_t)row * OUTC + kb * 8 + 4);
    u16x8 h;
    h[0] = f2b(a.x); h[1] = f2b(a.y); h[2] = f2b(a.z); h[3] = f2b(a.w);
    h[4] = f2b(b.x); h[5] = f2b(b.y); h[6] = f2b(b.z); h[7] = f2b(b.w);
    *(u16x8*)(hrm + (size_t)row * OUTC + kb * 8) = h;
  }
}

struct BPtrs {
  const float* W[4];
  const float* cw[4];
  const float* b[4];
  const float* cb[4];
};

// packed col p = j*128 + c*64 + g*16 + s  ->  gate g, orig col o = j*32 + c*16 + s
__global__ void k_packB(BPtrs bp, unsigned short* __restrict__ bpk,
                        float* __restrict__ bias_pk) {
  int t = blockIdx.x * blockDim.x + threadIdx.x;   // NKB*1024
  if (t >= NKB * 1024) return;
  int kb = t >> 10, p = t & 1023;
  int j = p >> 7, c = (p >> 6) & 1, g = (p >> 4) & 3, s = p & 15;
  int o = j * 32 + c * 16 + s;
  u16x8 h;
#pragma unroll
  for (int j8 = 0; j8 < 8; ++j8) {
    int k = kb * 8 + j8;
    float v = (k < 32) ? bp.W[g][k * OUTC + o]
                       : bp.cw[g][(size_t)(k - 32) * OUTC + o];
    h[j8] = f2b(v);
  }
  *(u16x8*)(bpk + (size_t)t * 8) = h;
  if (kb == 0) bias_pk[p] = bp.b[g][o] + bp.cb[g][o];
}

// ------- MFMA GEMM (R3-exact loop): BM=128 BN=128, 8 waves, 3-buf ring 48KB
// (3 blocks/CU), counted vmcnt(2), 2-tile-ahead prefetch. A staged directly
// from the 5 row-major single-writer buffers; per-tile uniform base select. -------

__device__ __forceinline__ float sigf(float x) {
  return __builtin_amdgcn_rcpf(1.0f + __expf(-x));
}
__device__ __forceinline__ float tanhfast(float x) {
  float e = __expf(2.0f * x);
  return 1.0f - 2.0f * __builtin_amdgcn_rcpf(e + 1.0f);
}

#define AS1(p) ((__attribute__((address_space(1))) void*)(p))
#define AS3(p) ((__attribute__((address_space(3))) void*)(p))

__global__ __launch_bounds__(512, 6) void k_gemm_mfma(
    const unsigned short* __restrict__ Xrm,   // [NN][32]
    const unsigned short* __restrict__ Hrm,   // [NN][256]
    const unsigned short* __restrict__ T1rm,  // [NN][256]
    const unsigned short* __restrict__ T2rm,  // [NN][256]
    const unsigned short* __restrict__ T3rm,  // [NN][256]
    const unsigned short* __restrict__ Bpk,   // [NKB][1024][8]
    const float* __restrict__ bias_pk,        // [1024] packed order
    const float* __restrict__ C,
    float* __restrict__ Hn, float* __restrict__ Cn) {
  __shared__ unsigned short Als[3][4 * 128 * 8];   // 3 x 8KB
  __shared__ unsigned short Bls[3][4 * 128 * 8];   // 3 x 8KB  (48KB total)

  // XCD-aware decode: b&7 = XCD; the 8 col-groups of one row-block run
  // consecutively on the same XCD (A panel stays in that XCD's L2)
  const int b = blockIdx.x;                 // 8*49*8 = 3136 blocks
  const int xcd = b & 7;
  const int slot = b >> 3;                  // 0..391
  const int cgrp = slot & 7;                // 8 col-groups of 128 packed cols
  const int rblk = xcd + ((slot >> 3) << 3);  // 0..391
  const int bm0 = rblk * 128;
  if (bm0 >= NN) return;                    // uniform whole-block exit
  const int cb0 = cgrp * 128;

  const int tid = threadIdx.x;
  const int lane = tid & 63;
  const int wid = tid >> 6;          // 8 waves
  const int wr = wid >> 1;           // row group (32 rows)
  const int wc = wid & 1;            // col half (64 packed cols)

  f32x4 acc[2][4];
#pragma unroll
  for (int i = 0; i < 2; ++i)
#pragma unroll
    for (int j = 0; j < 4; ++j) acc[i][j] = (f32x4){0.f, 0.f, 0.f, 0.f};

  // A staging: wave stages kbLocal = wid>>1, rows (wid&1)*64 + lane
  int a_row = bm0 + ((wid & 1) << 6) + lane;
  if (a_row > NN - 1) a_row = NN - 1;
  const size_t rowX = (size_t)a_row * INC;     // X row term
  const size_t row256 = (size_t)a_row * OUTC;  // H/T row term
  const int kbl8 = (wid >> 1) << 3;            // kb-in-tile * 8 elems
  // B staging: one 512-slot pass over [4kb][128pc]; idx = wid*64+lane
  const int idxw = wid << 6;                // wave-uniform base slot
  const unsigned short* bG =
      Bpk + (((size_t)(idxw >> 7)) * 1024 + cb0 + (idxw & 127) + lane) * 8;

  auto STAGE_A = [&](int buf, int tile) {
    const unsigned short* src;
    if (tile == 0)      src = Xrm + rowX;
    else if (tile < 9)  src = Hrm  + row256 + (size_t)(tile - 1) * 32;
    else if (tile < 17) src = T1rm + row256 + (size_t)(tile - 9) * 32;
    else if (tile < 25) src = T2rm + row256 + (size_t)(tile - 17) * 32;
    else                src = T3rm + row256 + (size_t)(tile - 25) * 32;
    __builtin_amdgcn_global_load_lds(AS1(src + kbl8),
                                     AS3(&Als[buf][(wid << 6) * 8]), 16, 0, 0);
  };
  auto STAGE_B = [&](int buf, int tile) {
    __builtin_amdgcn_global_load_lds(AS1(bG + ((size_t)(tile << 2)) * 1024 * 8),
                                     AS3(&Bls[buf][(wid << 6) * 8]), 16, 0, 0);
  };

  const int koff = lane >> 4;
  const int r15 = lane & 15;
  const int NT = NKB / 4;   // 33 tiles

  STAGE_A(0, 0); STAGE_B(0, 0);
  STAGE_A(1, 1); STAGE_B(1, 1);
  int cur = 0;
  for (int t = 0; t < NT; ++t) {
    // tile t's 2 loads are the oldest; t+1's 2 may remain in flight
    if (t < NT - 1)
      asm volatile("s_waitcnt vmcnt(2)\n\ts_barrier" ::: "memory");
    else
      asm volatile("s_waitcnt vmcnt(0)\n\ts_barrier" ::: "memory");

    const unsigned short* Ab = &Als[cur][((koff << 7) + (wr << 5) + r15) * 8];
    const unsigned short* Bb = &Bls[cur][((koff << 7) + (wc << 6) + r15) * 8];

    // read all frags, issue tile t+2 loads, then one 8-MFMA phase
    bf16x8 af0 = *(const bf16x8*)(Ab + 0 * 8);
    bf16x8 af1 = *(const bf16x8*)(Ab + 16 * 8);
    bf16x8 bf0 = *(const bf16x8*)(Bb + 0 * 8);
    bf16x8 bf1 = *(const bf16x8*)(Bb + 16 * 8);
    bf16x8 bf2 = *(const bf16x8*)(Bb + 32 * 8);
    bf16x8 bf3 = *(const bf16x8*)(Bb + 48 * 8);
    if (t + 2 < NT) { STAGE_A((t + 2) % 3, t + 2); STAGE_B((t + 2) % 3, t + 2); }
    __builtin_amdgcn_s_barrier();
    asm volatile("s_waitcnt lgkmcnt(0)" ::: "memory");
    __builtin_amdgcn_sched_barrier(0);
    __builtin_amdgcn_s_setprio(1);
    acc[0][0] = __builtin_amdgcn_mfma_f32_16x16x32_bf16(af0, bf0, acc[0][0], 0, 0, 0);
    acc[1][0] = __builtin_amdgcn_mfma_f32_16x16x32_bf16(af1, bf0, acc[1][0], 0, 0, 0);
    acc[0][1] = __builtin_amdgcn_mfma_f32_16x16x32_bf16(af0, bf1, acc[0][1], 0, 0, 0);
    acc[1][1] = __builtin_amdgcn_mfma_f32_16x16x32_bf16(af1, bf1, acc[1][1], 0, 0, 0);
    acc[0][2] = __builtin_amdgcn_mfma_f32_16x16x32_bf16(af0, bf2, acc[0][2], 0, 0, 0);
    acc[1][2] = __builtin_amdgcn_mfma_f32_16x16x32_bf16(af1, bf2, acc[1][2], 0, 0, 0);
    acc[0][3] = __builtin_amdgcn_mfma_f32_16x16x32_bf16(af0, bf3, acc[0][3], 0, 0, 0);
    acc[1][3] = __builtin_amdgcn_mfma_f32_16x16x32_bf16(af1, bf3, acc[1][3], 0, 0, 0);
    __builtin_amdgcn_s_setprio(0);

    cur = (cur + 1 == 3) ? 0 : cur + 1;
  }

  // fused LSTM epilogue: 4 gates of col ocol live in this thread's 4 n-frags
  const int ocol = cgrp * 32 + (wc << 4) + r15;
  float bz[4];
#pragma unroll
  for (int g = 0; g < 4; ++g) bz[g] = bias_pk[cb0 + (wc << 6) + (g << 4) + r15];

#pragma unroll
  for (int mi = 0; mi < 2; ++mi) {
    int rowb = bm0 + (wr << 5) + (mi << 4) + ((lane >> 4) << 2);
#pragma unroll
    for (int q = 0; q < 4; ++q) {
      int r = rowb + q;
      if (r >= NN) continue;
      float zi = acc[mi][0][q] + bz[0];
      float zf = acc[mi][1][q] + bz[1];
      float zc = acc[mi][2][q] + bz[2];
      float zo = acc[mi][3][q] + bz[3];
      float cold = C[(size_t)r * OUTC + ocol];
      float I = sigf(zi), F = sigf(zf), T = tanhfast(zc), O = sigf(zo);
      float cn = fmaf(F, cold, I * T);
      Cn[(size_t)r * OUTC + ocol] = cn;
      Hn[(size_t)r * OUTC + ocol] = O * tanhfast(cn);
    }
  }
}

// ---------------- launch ----------------

extern "C" void kernel_launch(void* const* d_in, const int* in_sizes, int n_in,
                              void* d_out, int out_size, void* d_ws, size_t ws_size,
                              hipStream_t stream) {
  const float* X = (const float*)d_in[0];
  const int* EI = (const int*)d_in[1];
  const float* EW = (const float*)d_in[2];
  const float* H = (const float*)d_in[3];
  const float* C = (const float*)d_in[4];

  char* ws = (char*)d_ws;
  size_t off = 0;
  auto alloc = [&](size_t bytes) -> void* {
    void* p = ws + off;
    off += (bytes + 255) & ~(size_t)255;
    return p;
  };
  int* row_ptr = (int*)alloc((NN + 1) * sizeof(int));
  int* cnt = (int*)alloc(NN * sizeof(int));
  int* nextp = (int*)alloc(NN * sizeof(int));
  int* bsum = (int*)alloc(128 * sizeof(int));
  Edge* ev = (Edge*)alloc(EE * sizeof(Edge));
  float* dis = (float*)alloc(NN * sizeof(float));
  unsigned short* Xrm = (unsigned short*)alloc((size_t)NN * INC * sizeof(unsigned short));
  unsigned short* Hrm = (unsigned short*)alloc((size_t)NN * OUTC * sizeof(unsigned short));
  unsigned short* T1rm = (unsigned short*)alloc((size_t)NN * OUTC * sizeof(unsigned short));
  unsigned short* T2rm = (unsigned short*)alloc((size_t)NN * OUTC * sizeof(unsigned short));
  unsigned short* T3rm = (unsigned short*)alloc((size_t)NN * OUTC * sizeof(unsigned short));
  unsigned short* Bpk = (unsigned short*)alloc((size_t)NKB * 1024 * 8 * sizeof(unsigned short));
  float* bias_pk = (float*)alloc(1024 * sizeof(float));
  (void)ws_size; (void)in_sizes; (void)n_in; (void)out_size;

  hipMemsetAsync(dis, 0, NN * sizeof(float), stream);
  hipMemsetAsync(cnt, 0, NN * sizeof(int), stream);

  const int ge = 1024;
  k_edge1<<<ge, 256, 0, stream>>>(EI, EW, dis, cnt);
  const int nscb = (NN + 511) / 512;   // 98
  k_scan1<<<nscb, 512, 0, stream>>>(cnt, row_ptr, bsum);
  k_scan2<<<1, 128, 0, stream>>>(bsum, row_ptr, nscb);
  k_scan3<<<(NN + 255) / 256, 256, 0, stream>>>(row_ptr, bsum, nextp, dis);
  k_fill<<<ge, 256, 0, stream>>>(EI, EW, dis, nextp, ev);

  k_packXH<<<(NN * 36 + 255) / 256, 256, 0, stream>>>(X, H, Xrm, Hrm);
  BPtrs bp;
  for (int g = 0; g < 4; ++g) {
    bp.W[g] = (const float*)d_in[5 + 4 * g];
    bp.b[g] = (const float*)d_in[6 + 4 * g];
    bp.cw[g] = (const float*)d_in[7 + 4 * g];
    bp.cb[g] = (const float*)d_in[8 + 4 * g];
  }
  k_packB<<<(NKB * 1024 + 255) / 256, 256, 0, stream>>>(bp, Bpk, bias_pk);

  const int pgrid = (NN + 3) / 4;
  k_prop_bf<<<pgrid, 256, 0, stream>>>(row_ptr, ev, Hrm, nullptr, 1.f, T1rm);
  k_prop_bf<<<pgrid, 256, 0, stream>>>(row_ptr, ev, T1rm, Hrm, 2.f, T2rm);
  k_prop_bf<<<pgrid, 256, 0, stream>>>(row_ptr, ev, T2rm, T1rm, 2.f, T3rm);

  float* Hn = (float*)d_out;
  float* Cn = (float*)d_out + (size_t)NN * OUTC;
  k_gemm_mfma<<<8 * 49 * 8, 512, 0, stream>>>(Xrm, Hrm, T1rm, T2rm, T3rm,
                                              Bpk, bias_pk, C, Hn, Cn);
}

// Round 7
// 487.581 us; speedup vs baseline: 1.1183x; 1.1183x over previous
//
#include <hip/hip_runtime.h>
#include <math.h>

#define NN   50000
#define EE   800000
#define INC  32
#define OUTC 256
#define NKB  132     // 1056/8 k-blocks: X kb0-3, H kb4-35, T1 36-67, T2 68-99, T3 100-131

using bf16x8 = __attribute__((ext_vector_type(8))) short;
using u16x8  = __attribute__((ext_vector_type(8))) unsigned short;
using f32x4  = __attribute__((ext_vector_type(4))) float;

struct __align__(8) Edge { int s; float w; };

__device__ __forceinline__ unsigned short f2b(float f) {
  union { float f; unsigned u; } v; v.f = f;
  return (unsigned short)((v.u + 0x7FFFu + ((v.u >> 16) & 1u)) >> 16);
}
__device__ __forceinline__ float b2f(unsigned short u) {
  union { unsigned u; float f; } v; v.u = ((unsigned)u) << 16; return v.f;
}

// ---------------- graph normalization + CSC build ----------------

__global__ void k_edge1(const int* __restrict__ ei, const float* __restrict__ ew,
                        float* __restrict__ deg, int* __restrict__ cnt) {
  for (int e = blockIdx.x * blockDim.x + threadIdx.x; e < EE;
       e += gridDim.x * blockDim.x) {
    atomicAdd(&deg[ei[e]], ew[e]);        // src degree
    atomicAdd(&cnt[ei[EE + e]], 1);       // dst histogram
  }
}

// hierarchical scan: 98 blocks x 512
__global__ __launch_bounds__(512) void k_scan1(const int* __restrict__ cnt,
                                               int* __restrict__ row_ptr,
                                               int* __restrict__ bsum) {
  __shared__ int sd[512];
  int t = threadIdx.x;
  int i = blockIdx.x * 512 + t;
  int x = (i < NN) ? cnt[i] : 0;
  sd[t] = x;
  __syncthreads();
  for (int off = 1; off < 512; off <<= 1) {
    int v = (t >= off) ? sd[t - off] : 0;
    __syncthreads();
    sd[t] += v;
    __syncthreads();
  }
  if (i < NN) row_ptr[i] = sd[t] - x;     // block-local exclusive
  if (t == 511) bsum[blockIdx.x] = sd[511];
}

__global__ __launch_bounds__(128) void k_scan2(int* __restrict__ bsum,
                                               int* __restrict__ row_ptr,
                                               int nblk) {
  __shared__ int sd[128];
  int t = threadIdx.x;
  int x = (t < nblk) ? bsum[t] : 0;
  sd[t] = x;
  __syncthreads();
  for (int off = 1; off < 128; off <<= 1) {
    int v = (t >= off) ? sd[t - off] : 0;
    __syncthreads();
    sd[t] += v;
    __syncthreads();
  }
  if (t < nblk) bsum[t] = sd[t] - x;      // exclusive
  if (t == 127) row_ptr[NN] = sd[127];
}

// adds block offsets; also finalizes dis = rsqrt(deg)
__global__ void k_scan3(int* __restrict__ row_ptr, const int* __restrict__ bsum,
                        int* __restrict__ nxt, float* __restrict__ deg) {
  int i = blockIdx.x * blockDim.x + threadIdx.x;
  if (i < NN) {
    int v = row_ptr[i] + bsum[i >> 9];
    row_ptr[i] = v;
    nxt[i] = v;
    float d = deg[i];
    deg[i] = d > 0.f ? rsqrtf(d) : 0.f;
  }
}

__global__ void k_fill(const int* __restrict__ ei, const float* __restrict__ ew,
                       const float* __restrict__ dis, int* __restrict__ nxt,
                       Edge* __restrict__ ev) {
  for (int e = blockIdx.x * blockDim.x + threadIdx.x; e < EE;
       e += gridDim.x * blockDim.x) {
    int s = ei[e], d = ei[EE + e];
    int pos = atomicAdd(&nxt[d], 1);
    Edge eg; eg.s = s; eg.w = -dis[s] * ew[e] * dis[d];  // -(2/lam)=-1, diag=0
    ev[pos] = eg;
  }
}

// -------- bf16 sparse prop: out = scale*(A~ x) - init (row-major only) --------

__global__ __launch_bounds__(256) void k_prop_bf(
    const int* __restrict__ row_ptr, const Edge* __restrict__ ev,
    const unsigned short* __restrict__ xb,
    const unsigned short* __restrict__ initb, float scale,
    unsigned short* __restrict__ outb) {
  int wid = blockIdx.x * 4 + (threadIdx.x >> 6);
  if (wid >= NN) return;
  int lane = threadIdx.x & 63;
  int half = lane >> 5;
  int cl = lane & 31;                       // col block: cols cl*8..cl*8+7
  int start = __builtin_amdgcn_readfirstlane(row_ptr[wid]);
  int end = __builtin_amdgcn_readfirstlane(row_ptr[wid + 1]);
  const size_t cofs = (size_t)(cl << 3);

  float a0[8], a1[8], a2[8], a3[8];
#pragma unroll
  for (int i = 0; i < 8; ++i) { a0[i] = 0.f; a1[i] = 0.f; a2[i] = 0.f; a3[i] = 0.f; }

  int j = start;
  for (; j + 7 < end; j += 8) {             // 8 edges per iter (4 per half)
    Edge e0 = ev[j + half];
    Edge e1 = ev[j + 2 + half];
    Edge e2 = ev[j + 4 + half];
    Edge e3 = ev[j + 6 + half];
    u16x8 u0 = *(const u16x8*)(xb + (size_t)e0.s * OUTC + cofs);
    u16x8 u1 = *(const u16x8*)(xb + (size_t)e1.s * OUTC + cofs);
    u16x8 u2 = *(const u16x8*)(xb + (size_t)e2.s * OUTC + cofs);
    u16x8 u3 = *(const u16x8*)(xb + (size_t)e3.s * OUTC + cofs);
#pragma unroll
    for (int i = 0; i < 8; ++i) {
      a0[i] = fmaf(e0.w, b2f(u0[i]), a0[i]);
      a1[i] = fmaf(e1.w, b2f(u1[i]), a1[i]);
      a2[i] = fmaf(e2.w, b2f(u2[i]), a2[i]);
      a3[i] = fmaf(e3.w, b2f(u3[i]), a3[i]);
    }
  }
  for (; j + 1 < end; j += 2) {             // pair tail
    Edge e0 = ev[j + half];
    u16x8 u0 = *(const u16x8*)(xb + (size_t)e0.s * OUTC + cofs);
#pragma unroll
    for (int i = 0; i < 8; ++i) a0[i] = fmaf(e0.w, b2f(u0[i]), a0[i]);
  }
  if (j < end) {                            // odd edge: half 0 only
    Edge e0 = ev[j];
    float wv = half ? 0.f : e0.w;
    u16x8 u0 = *(const u16x8*)(xb + (size_t)e0.s * OUTC + cofs);
#pragma unroll
    for (int i = 0; i < 8; ++i) a0[i] = fmaf(wv, b2f(u0[i]), a0[i]);
  }

  float o[8];
#pragma unroll
  for (int i = 0; i < 8; ++i) {
    float s = (a0[i] + a1[i]) + (a2[i] + a3[i]);
    s += __shfl_xor(s, 32);
    o[i] = s;
  }
  if (initb) {
    u16x8 iv = *(const u16x8*)(initb + (size_t)wid * OUTC + cofs);
#pragma unroll
    for (int i = 0; i < 8; ++i) o[i] = scale * o[i] - b2f(iv[i]);
  }
  if (half == 1) {
    u16x8 h;
#pragma unroll
    for (int i = 0; i < 8; ++i) h[i] = f2b(o[i]);
    *(u16x8*)(outb + (size_t)wid * OUTC + cofs) = h;
  }
}

// ---------------- bf16 packing of X+H (row-major, separate buffers) ----------------

__global__ void k_packXH(const float* __restrict__ X, const float* __restrict__ H,
                         unsigned short* __restrict__ xrm,
                         unsigned short* __restrict__ hrm) {
  int t = blockIdx.x * blockDim.x + threadIdx.x;   // NN*4 + NN*32
  if (t < NN * 4) {
    int row = t >> 2, kb = t & 3;
    float4 a = *(const float4*)(X + (size_t)row * INC + kb * 8);
    float4 b = *(const float4*)(X + (size_t)row * INC + kb * 8 + 4);
    u16x8 h;
    h[0] = f2b(a.x); h[1] = f2b(a.y); h[2] = f2b(a.z); h[3] = f2b(a.w);
    h[4] = f2b(b.x); h[5] = f2b(b.y); h[6] = f2b(b.z); h[7] = f2b(b.w);
    *(u16x8*)(xrm + (size_t)row * INC + kb * 8) = h;
  } else if (t < NN * 36) {
    int u = t - NN * 4;
    int row = u >> 5, kb = u & 31;
    float4 a = *(const float4*)(H + (size_t)row * OUTC + kb * 8);
    float4 b = *(const float4*)(H + (size_t)row * OUTC + kb * 8 + 4);
    u16x8 h;
    h[0] = f2b(a.x); h[1] = f2b(a.y); h[2] = f2b(a.z); h[3] = f2b(a.w);
    h[4] = f2b(b.x); h[5] = f2b(b.y); h[6] = f2b(b.z); h[7] = f2b(b.w);
    *(u16x8*)(hrm + (size_t)row * OUTC + kb * 8) = h;
  }
}

struct BPtrs {
  const float* W[4];
  const float* cw[4];
  const float* b[4];
  const float* cb[4];
};

// packed col p = j*128 + c*64 + g*16 + s  ->  gate g, orig col o = j*32 + c*16 + s
__global__ void k_packB(BPtrs bp, unsigned short* __restrict__ bpk,
                        float* __restrict__ bias_pk) {
  int t = blockIdx.x * blockDim.x + threadIdx.x;   // NKB*1024
  if (t >= NKB * 1024) return;
  int kb = t >> 10, p = t & 1023;
  int j = p >> 7, c = (p >> 6) & 1, g = (p >> 4) & 3, s = p & 15;
  int o = j * 32 + c * 16 + s;
  u16x8 h;
#pragma unroll
  for (int j8 = 0; j8 < 8; ++j8) {
    int k = kb * 8 + j8;
    float v = (k < 32) ? bp.W[g][k * OUTC + o]
                       : bp.cw[g][(size_t)(k - 32) * OUTC + o];
    h[j8] = f2b(v);
  }
  *(u16x8*)(bpk + (size_t)t * 8) = h;
  if (kb == 0) bias_pk[p] = bp.b[g][o] + bp.cb[g][o];
}

// ------- MFMA GEMM (R3 loop): BM=128 BN=128, 8 waves, 3-buf ring 48KB
// (3 blocks/CU), counted vmcnt(2), 2-tile-ahead prefetch.
// A staged from row-major buffers with SECTOR-COALESCED lane grouping:
// wave stages 16 rows x 64B (lane>>2 = row, lane&3 = 16B piece); LDS A layout
// [row(128)][slot(4)][16B] with XOR swizzle slot = kb ^ ((row>>1)&3) applied
// at BOTH the DMA source and the ds_read (rule: both-sides-or-neither).
// Within each 16-lane ds_read_b128 phase the addresses cycle all 8 bank
// groups twice -> 2 lanes/bank = conflict-free. -------

__device__ __forceinline__ float sigf(float x) {
  return __builtin_amdgcn_rcpf(1.0f + __expf(-x));
}
__device__ __forceinline__ float tanhfast(float x) {
  float e = __expf(2.0f * x);
  return 1.0f - 2.0f * __builtin_amdgcn_rcpf(e + 1.0f);
}

#define AS1(p) ((__attribute__((address_space(1))) void*)(p))
#define AS3(p) ((__attribute__((address_space(3))) void*)(p))

__global__ __launch_bounds__(512, 6) void k_gemm_mfma(
    const unsigned short* __restrict__ Xrm,   // [NN][32]
    const unsigned short* __restrict__ Hrm,   // [NN][256]
    const unsigned short* __restrict__ T1rm,  // [NN][256]
    const unsigned short* __restrict__ T2rm,  // [NN][256]
    const unsigned short* __restrict__ T3rm,  // [NN][256]
    const unsigned short* __restrict__ Bpk,   // [NKB][1024][8]
    const float* __restrict__ bias_pk,        // [1024] packed order
    const float* __restrict__ C,
    float* __restrict__ Hn, float* __restrict__ Cn) {
  __shared__ unsigned short Als[3][128 * 4 * 8];   // 3 x 8KB, [row][slot][8]
  __shared__ unsigned short Bls[3][4 * 128 * 8];   // 3 x 8KB  (48KB total)

  const int b = blockIdx.x;                 // 8*49*8 = 3136 blocks
  const int xcd = b & 7;
  const int slot = b >> 3;                  // 0..391
  const int cgrp = slot & 7;                // 8 col-groups of 128 packed cols
  const int rblk = xcd + ((slot >> 3) << 3);  // 0..391
  const int bm0 = rblk * 128;
  if (bm0 >= NN) return;                    // uniform whole-block exit
  const int cb0 = cgrp * 128;

  const int tid = threadIdx.x;
  const int lane = tid & 63;
  const int wid = tid >> 6;          // 8 waves
  const int wr = wid >> 1;           // row group (32 rows)
  const int wc = wid & 1;            // col half (64 packed cols)

  f32x4 acc[2][4];
#pragma unroll
  for (int i = 0; i < 2; ++i)
#pragma unroll
    for (int j = 0; j < 4; ++j) acc[i][j] = (f32x4){0.f, 0.f, 0.f, 0.f};

  // A staging: wave stages rows wid*16..wid*16+15; lane>>2 = row-in-group,
  // lane&3 = 16B piece, piece fetched = (lane&3) ^ ((row>>1)&3)  [swizzle]
  const int sr = lane >> 2;
  const int scs = (lane & 3) ^ ((sr >> 1) & 3);
  int arow = bm0 + (wid << 4) + sr;
  if (arow > NN - 1) arow = NN - 1;
  const size_t rowA32 = (size_t)arow * INC + ((size_t)scs << 3);
  const size_t rowA256 = (size_t)arow * OUTC + ((size_t)scs << 3);
  // B staging: one 512-slot pass over [4kb][128pc]; idx = wid*64+lane
  const int idxw = wid << 6;                // wave-uniform base slot
  const unsigned short* bG =
      Bpk + (((size_t)(idxw >> 7)) * 1024 + cb0 + (idxw & 127) + lane) * 8;

  auto STAGE_A = [&](int buf, int tile) {
    const unsigned short* src;
    if (tile == 0)      src = Xrm + rowA32;
    else if (tile < 9)  src = Hrm  + rowA256 + (size_t)(tile - 1) * 32;
    else if (tile < 17) src = T1rm + rowA256 + (size_t)(tile - 9) * 32;
    else if (tile < 25) src = T2rm + rowA256 + (size_t)(tile - 17) * 32;
    else                src = T3rm + rowA256 + (size_t)(tile - 25) * 32;
    __builtin_amdgcn_global_load_lds(AS1(src),
                                     AS3(&Als[buf][wid << 9]), 16, 0, 0);
  };
  auto STAGE_B = [&](int buf, int tile) {
    __builtin_amdgcn_global_load_lds(AS1(bG + ((size_t)(tile << 2)) * 1024 * 8),
                                     AS3(&Bls[buf][(wid << 6) * 8]), 16, 0, 0);
  };

  const int koff = lane >> 4;
  const int r15 = lane & 15;
  const int NT = NKB / 4;   // 33 tiles

  STAGE_A(0, 0); STAGE_B(0, 0);
  STAGE_A(1, 1); STAGE_B(1, 1);
  int cur = 0;
  for (int t = 0; t < NT; ++t) {
    // tile t's 2 loads are the oldest; t+1's 2 may remain in flight
    if (t < NT - 1)
      asm volatile("s_waitcnt vmcnt(2)\n\ts_barrier" ::: "memory");
    else
      asm volatile("s_waitcnt vmcnt(0)\n\ts_barrier" ::: "memory");

    // A read: row0 = wr*32 + r15 (af0), +16 (af1, same swizzle: 16 = 0 mod 4)
    const int row0 = (wr << 5) + r15;
    const int asw = (r15 >> 1) & 3;        // == (row0>>1)&3 since wr*32>>1 = 0 mod 4
    const unsigned short* Ab = &Als[cur][row0 * 32 + ((koff ^ asw) << 3)];
    const unsigned short* Bb = &Bls[cur][((koff << 7) + (wc << 6) + r15) * 8];

    bf16x8 af0 = *(const bf16x8*)(Ab);
    bf16x8 af1 = *(const bf16x8*)(Ab + 512);     // +16 rows * 32 ush
    bf16x8 bf0 = *(const bf16x8*)(Bb + 0 * 8);
    bf16x8 bf1 = *(const bf16x8*)(Bb + 16 * 8);
    bf16x8 bf2 = *(const bf16x8*)(Bb + 32 * 8);
    bf16x8 bf3 = *(const bf16x8*)(Bb + 48 * 8);
    if (t + 2 < NT) { STAGE_A((t + 2) % 3, t + 2); STAGE_B((t + 2) % 3, t + 2); }
    __builtin_amdgcn_s_barrier();
    asm volatile("s_waitcnt lgkmcnt(0)" ::: "memory");
    __builtin_amdgcn_sched_barrier(0);
    __builtin_amdgcn_s_setprio(1);
    acc[0][0] = __builtin_amdgcn_mfma_f32_16x16x32_bf16(af0, bf0, acc[0][0], 0, 0, 0);
    acc[1][0] = __builtin_amdgcn_mfma_f32_16x16x32_bf16(af1, bf0, acc[1][0], 0, 0, 0);
    acc[0][1] = __builtin_amdgcn_mfma_f32_16x16x32_bf16(af0, bf1, acc[0][1], 0, 0, 0);
    acc[1][1] = __builtin_amdgcn_mfma_f32_16x16x32_bf16(af1, bf1, acc[1][1], 0, 0, 0);
    acc[0][2] = __builtin_amdgcn_mfma_f32_16x16x32_bf16(af0, bf2, acc[0][2], 0, 0, 0);
    acc[1][2] = __builtin_amdgcn_mfma_f32_16x16x32_bf16(af1, bf2, acc[1][2], 0, 0, 0);
    acc[0][3] = __builtin_amdgcn_mfma_f32_16x16x32_bf16(af0, bf3, acc[0][3], 0, 0, 0);
    acc[1][3] = __builtin_amdgcn_mfma_f32_16x16x32_bf16(af1, bf3, acc[1][3], 0, 0, 0);
    __builtin_amdgcn_s_setprio(0);

    cur = (cur + 1 == 3) ? 0 : cur + 1;
  }

  // fused LSTM epilogue: 4 gates of col ocol live in this thread's 4 n-frags
  const int ocol = cgrp * 32 + (wc << 4) + r15;
  float bz[4];
#pragma unroll
  for (int g = 0; g < 4; ++g) bz[g] = bias_pk[cb0 + (wc << 6) + (g << 4) + r15];

#pragma unroll
  for (int mi = 0; mi < 2; ++mi) {
    int rowb = bm0 + (wr << 5) + (mi << 4) + ((lane >> 4) << 2);
#pragma unroll
    for (int q = 0; q < 4; ++q) {
      int r = rowb + q;
      if (r >= NN) continue;
      float zi = acc[mi][0][q] + bz[0];
      float zf = acc[mi][1][q] + bz[1];
      float zc = acc[mi][2][q] + bz[2];
      float zo = acc[mi][3][q] + bz[3];
      float cold = C[(size_t)r * OUTC + ocol];
      float I = sigf(zi), F = sigf(zf), T = tanhfast(zc), O = sigf(zo);
      float cn = fmaf(F, cold, I * T);
      Cn[(size_t)r * OUTC + ocol] = cn;
      Hn[(size_t)r * OUTC + ocol] = O * tanhfast(cn);
    }
  }
}

// ---------------- launch ----------------

extern "C" void kernel_launch(void* const* d_in, const int* in_sizes, int n_in,
                              void* d_out, int out_size, void* d_ws, size_t ws_size,
                              hipStream_t stream) {
  const float* X = (const float*)d_in[0];
  const int* EI = (const int*)d_in[1];
  const float* EW = (const float*)d_in[2];
  const float* H = (const float*)d_in[3];
  const float* C = (const float*)d_in[4];

  char* ws = (char*)d_ws;
  size_t off = 0;
  auto alloc = [&](size_t bytes) -> void* {
    void* p = ws + off;
    off += (bytes + 255) & ~(size_t)255;
    return p;
  };
  int* row_ptr = (int*)alloc((NN + 1) * sizeof(int));
  int* cnt = (int*)alloc(NN * sizeof(int));
  int* nextp = (int*)alloc(NN * sizeof(int));
  int* bsum = (int*)alloc(128 * sizeof(int));
  Edge* ev = (Edge*)alloc(EE * sizeof(Edge));
  float* dis = (float*)alloc(NN * sizeof(float));
  unsigned short* Xrm = (unsigned short*)alloc((size_t)NN * INC * sizeof(unsigned short));
  unsigned short* Hrm = (unsigned short*)alloc((size_t)NN * OUTC * sizeof(unsigned short));
  unsigned short* T1rm = (unsigned short*)alloc((size_t)NN * OUTC * sizeof(unsigned short));
  unsigned short* T2rm = (unsigned short*)alloc((size_t)NN * OUTC * sizeof(unsigned short));
  unsigned short* T3rm = (unsigned short*)alloc((size_t)NN * OUTC * sizeof(unsigned short));
  unsigned short* Bpk = (unsigned short*)alloc((size_t)NKB * 1024 * 8 * sizeof(unsigned short));
  float* bias_pk = (float*)alloc(1024 * sizeof(float));
  (void)ws_size; (void)in_sizes; (void)n_in; (void)out_size;

  hipMemsetAsync(dis, 0, NN * sizeof(float), stream);
  hipMemsetAsync(cnt, 0, NN * sizeof(int), stream);

  const int ge = 1024;
  k_edge1<<<ge, 256, 0, stream>>>(EI, EW, dis, cnt);
  const int nscb = (NN + 511) / 512;   // 98
  k_scan1<<<nscb, 512, 0, stream>>>(cnt, row_ptr, bsum);
  k_scan2<<<1, 128, 0, stream>>>(bsum, row_ptr, nscb);
  k_scan3<<<(NN + 255) / 256, 256, 0, stream>>>(row_ptr, bsum, nextp, dis);
  k_fill<<<ge, 256, 0, stream>>>(EI, EW, dis, nextp, ev);

  k_packXH<<<(NN * 36 + 255) / 256, 256, 0, stream>>>(X, H, Xrm, Hrm);
  BPtrs bp;
  for (int g = 0; g < 4; ++g) {
    bp.W[g] = (const float*)d_in[5 + 4 * g];
    bp.b[g] = (const float*)d_in[6 + 4 * g];
    bp.cw[g] = (const float*)d_in[7 + 4 * g];
    bp.cb[g] = (const float*)d_in[8 + 4 * g];
  }
  k_packB<<<(NKB * 1024 + 255) / 256, 256, 0, stream>>>(bp, Bpk, bias_pk);

  const int pgrid = (NN + 3) / 4;
  k_prop_bf<<<pgrid, 256, 0, stream>>>(row_ptr, ev, Hrm, nullptr, 1.f, T1rm);
  k_prop_bf<<<pgrid, 256, 0, stream>>>(row_ptr, ev, T1rm, Hrm, 2.f, T2rm);
  k_prop_bf<<<pgrid, 256, 0, stream>>>(row_ptr, ev, T2rm, T1rm, 2.f, T3rm);

  float* Hn = (float*)d_out;
  float* Cn = (float*)d_out + (size_t)NN * OUTC;
  k_gemm_mfma<<<8 * 49 * 8, 512, 0, stream>>>(Xrm, Hrm, T1rm, T2rm, T3rm,
                                              Bpk, bias_pk, C, Hn, Cn);
}